// Round 8
// baseline (121.713 us; speedup 1.0000x reference)
//
#include <hip/hip_runtime.h>

// Problem constants (fixed shapes from the reference).
constexpr int B = 2, C = 320, H = 128, W = 240;
constexpr int G = 40, CPG = 8, MAXD = 48;
constexpr int HW = H * W;
constexpr int NROW = B * G * H;        // 10240 (b,g,h) rows
constexpr int ROWS_PER_BLOCK = 4;      // 4 waves/block, one row each, consecutive h
constexpr int W4 = W / 4;              // 60 float4 per channel row

typedef float f32x4 __attribute__((ext_vector_type(4)));

// Address-space-qualified void types for global_load_lds.
typedef const __attribute__((address_space(1))) void g_void;
typedef __attribute__((address_space(3))) void lds_void;

// out[b,g,d,h,x] = (1/CPG) * sum_k L[b, g*CPG+k, h, x] * R[b, g*CPG+k, h, x-d]  (x>=d, else 0)
//
// R8 vs R7: halve the sync domain + double-buffer the writeback.
//  - 256-thread blocks (4 waves, 4 consecutive h rows). LDS = 30.7K staging +
//    7.7K wb -> 38.4KB -> 4 blocks/CU (16 waves/CU, same as R7, but 4
//    INDEPENDENT barrier domains per CU -> decorrelated barrier stalls).
//  - wb double-buffered, one d-slice per phase -> exactly ONE barrier per
//    phase (the lgkm(0) before each barrier also retires the previous
//    phase's ds_reads, so buffer reuse two phases later is safe). Global
//    stores of slice p overlap ds_writes of slice p+1.
//  - Store chunks stay dense: 4 rows x 960B = 3840B = 30 full 128B lines.
//  - Kept from R5/R7: nt loads, gload_lds staging, single vmcnt(0) head,
//    nt stores, raw s_barrier (never drains vmcnt).
__global__ __launch_bounds__(256) void gwc_volume_kernel(
    const float* __restrict__ left, const float* __restrict__ right,
    float* __restrict__ out)
{
    const int tid  = threadIdx.x;
    const int wv   = tid >> 6;   // wave id within block -> which row (0..3)
    const int lane = tid & 63;
    const int row  = blockIdx.x * ROWS_PER_BLOCK + wv;

    const int h  = row % H;
    const int h0 = h - wv;       // block's first h row (4 | H, never straddles (b,g))
    const int bg = row / H;
    const int g  = bg % G;
    const int b  = bg / G;

    // Staged right rows: 4 waves x 480 float4 = 30.7 KB (linear, gload_lds dest).
    __shared__ f32x4 sR4[ROWS_PER_BLOCK][CPG * W4];
    // Double-buffered writeback: one d-slice (4 rows x 60 f32x4) per buffer.
    __shared__ f32x4 wb[2][ROWS_PER_BLOCK][W4];

    const size_t in_base = ((size_t)(b * C + g * CPG) * H + h) * (size_t)W;

    const int t = lane;                  // x-tile index, x = 4t..4t+3
    const bool active = (t < W4);        // lanes 60..63: staging + barriers only

    // ---- issue LEFT loads first (registers), so they fly with R staging ----
    f32x4 Lv[CPG];
    if (active) {
        #pragma unroll
        for (int k = 0; k < CPG; ++k)
            Lv[k] = __builtin_nontemporal_load(
                reinterpret_cast<const f32x4*>(left + in_base + (size_t)k * HW + 4 * t));
    }

    // ---- stage RIGHT row: direct HBM -> LDS, 8 x (64 lanes x 16 B) chunks ----
    #pragma unroll
    for (int i = 0; i < 8; ++i) {
        const int j = i * 64 + lane;     // float4 index: j = k*60 + x4
        if (j < CPG * W4) {
            const int k  = j / W4;
            const int x4 = j - k * W4;
            const float* src = right + in_base + (size_t)k * HW + 4 * x4;
            char* dst = (char*)&sR4[wv][0] + (size_t)i * 1024;
            __builtin_amdgcn_global_load_lds((g_void*)src, (lds_void*)dst, 16, 0, 0);
        }
    }

    // One drain for BOTH batches (L regs + LDS staging), then compute.
    asm volatile("s_waitcnt vmcnt(0)" ::: "memory");
    __builtin_amdgcn_sched_barrier(0);

    const f32x4* sr = &sR4[wv][0];
    // Base (in floats) of the block's 4-row chunk in d-slice 0 of this (b,g).
    const size_t chunk00 = ((size_t)bg * MAXD * H + h0) * (size_t)W;

    // ---- 12 disparity groups of 4 ----
    #pragma unroll 1
    for (int dg = 0; dg < MAXD / 4; ++dg) {
        float acc[4][4];
        #pragma unroll
        for (int dd = 0; dd < 4; ++dd)
            #pragma unroll
            for (int xx = 0; xx < 4; ++xx) acc[dd][xx] = 0.f;

        if (active && t >= dg) {         // t < dg: whole tile in the zero wedge
            #pragma unroll
            for (int k = 0; k < CPG; ++k) {
                const int base = k * W4 + (t - dg);
                const f32x4 hi = sr[base];                   // R[A .. A+3]
                f32x4 lo;
                if (t > dg) lo = sr[base - 1];               // R[A-4 .. A-1]
                else        lo = (f32x4){0.f, 0.f, 0.f, 0.f}; // x<d -> zeros
                float win[8];
                win[0] = lo.x; win[1] = lo.y; win[2] = lo.z; win[3] = lo.w;
                win[4] = hi.x; win[5] = hi.y; win[6] = hi.z; win[7] = hi.w;
                // r-index = A + xx - dd -> win[4 + xx - dd]
                #pragma unroll
                for (int dd = 0; dd < 4; ++dd)
                    #pragma unroll
                    for (int xx = 0; xx < 4; ++xx)
                        acc[dd][xx] += Lv[k][xx] * win[4 + xx - dd];
            }
        }

        // ---- 4 single-slice writeback phases, double-buffered, 1 barrier each ----
        #pragma unroll
        for (int dd = 0; dd < 4; ++dd) {
            const int buf = (dg * 4 + dd) & 1;
            if (active) {
                f32x4 o;
                o.x = acc[dd][0] * 0.125f;
                o.y = acc[dd][1] * 0.125f;
                o.z = acc[dd][2] * 0.125f;
                o.w = acc[dd][3] * 0.125f;
                wb[buf][wv][t] = o;
            }
            // lgkm(0) retires our ds_write AND our previous phase's ds_read
            // (making buffer reuse safe); barrier makes all waves' writes
            // visible. No vmcnt drain — global stores stay in flight.
            asm volatile("s_waitcnt lgkmcnt(0)" ::: "memory");
            __builtin_amdgcn_s_barrier();
            __builtin_amdgcn_sched_barrier(0);

            // Cooperative dense store: 240 f32x4 = 4 rows x 960B = 3840B,
            // 3840-aligned (h0 % 4 == 0) -> 30 full 128B lines.
            if (tid < ROWS_PER_BLOCK * W4) {
                const int r  = tid / W4;
                const int x4 = tid - r * W4;
                const f32x4 v = wb[buf][r][x4];
                __builtin_nontemporal_store(
                    v, reinterpret_cast<f32x4*>(
                        out + chunk00 + (size_t)(dg * 4 + dd) * HW +
                        (size_t)r * W + 4 * x4));
            }
        }
    }
}

extern "C" void kernel_launch(void* const* d_in, const int* in_sizes, int n_in,
                              void* d_out, int out_size, void* d_ws, size_t ws_size,
                              hipStream_t stream) {
    const float* left  = (const float*)d_in[0];
    const float* right = (const float*)d_in[1];
    float* out = (float*)d_out;

    dim3 grid(NROW / ROWS_PER_BLOCK);   // 2560 blocks
    dim3 block(256);                    // 4 waves, 4 consecutive h rows of one (b,g)
    hipLaunchKernelGGL(gwc_volume_kernel, grid, block, 0, stream,
                       left, right, out);
}